// Round 11
// baseline (168.776 us; speedup 1.0000x reference)
//
#include <hip/hip_runtime.h>

#define B_ 8
#define C_ 256
#define HW_ 2304
#define E_ 64
#define SB_ (C_*HW_)  // 589824 floats per batch
#define LOG2E_ 1.44269504088896340736f

typedef unsigned short u16;
typedef __attribute__((ext_vector_type(8))) __bf16 bf16x8;
typedef __attribute__((ext_vector_type(4))) float f32x4;
typedef __attribute__((ext_vector_type(16))) float f32x16;
#define MFMA16(a,b,c) __builtin_amdgcn_mfma_f32_16x16x32_bf16(a,b,c,0,0,0)
#define MFMA32(a,b,c) __builtin_amdgcn_mfma_f32_32x32x16_bf16(a,b,c,0,0,0)

// LDS write->read ordering (epilogue only)
#define LDS_FENCE() do { asm volatile("s_waitcnt lgkmcnt(0)" ::: "memory"); \
                         __builtin_amdgcn_sched_barrier(0); } while(0)

// swap row1 of a with row0 of b: after, a = pf-word(w), b = pf-word(w+2)
#define PSWAP(a,b) asm("v_permlane32_swap_b32 %0, %1" : "+v"(a), "+v"(b))

// fp32 -> bf16 RNE via integer ops (scalar path)
static __device__ inline u16 f2bf(float x){
  unsigned u = __builtin_bit_cast(unsigned, x);
  u += 0x7FFFu + ((u >> 16) & 1u);
  return (u16)(u >> 16);
}
static __device__ inline float bf2f(u16 h){
  unsigned u = ((unsigned)h) << 16;
  return __builtin_bit_cast(float, u);
}
static __device__ __forceinline__ unsigned cvtpk_bf16(float a, float b){
  unsigned r;
  asm("v_cvt_pk_bf16_f32 %0, %1, %2" : "=v"(r) : "v"(a), "v"(b));
  return r;
}
// split 2 floats into packed hi-bf16 word and packed lo-residual word
static __device__ __forceinline__ void split2(float x0, float x1, unsigned &H, unsigned &L){
  H = cvtpk_bf16(x0, x1);
  float h0 = __builtin_bit_cast(float, H << 16);
  float h1 = __builtin_bit_cast(float, H & 0xFFFF0000u);
  L = cvtpk_bf16(x0 - h0, x1 - h1);
}

// Fragment-contiguous layouts (u16 units), lane = g*16 + l15:
//  Q/K:  (tile*2 + kc)*512 + lane*8 + u ; tile = b*144 + pos/16, value (pos=tile*16+l15, e=kc*32+g*8+u)
//  V:    ((b*72 + ic)*4 + es)*512 + lane*8 + u ; value (e=es*16+l15, i=ic*32+g*8+u)
//  attc: ((b*16 + jt)*8 + kc)*512 + lane*8 + u ; value (j=jt*16+l15, i=kc*32+g*8+u)
//  W:    ((mz*4 + m)*8 + kc)*512 + lane*8 + u  ; value (e=m*16+l15, c=kc*32+g*8+u)
// NOTE: K (mz==1) is pre-scaled by log2e so downstream softmax uses exp2.

struct KFrag { bf16x8 h0, h1, l0, l1; };
static __device__ __forceinline__ KFrag ldfrag(const u16* __restrict__ ph,
                                               const u16* __restrict__ pl,
                                               size_t tile, int lane){
  KFrag q;
  q.h0 = *(const bf16x8*)(ph + (tile*2+0)*512 + (size_t)lane*8);
  q.h1 = *(const bf16x8*)(ph + (tile*2+1)*512 + (size_t)lane*8);
  q.l0 = *(const bf16x8*)(pl + (tile*2+0)*512 + (size_t)lane*8);
  q.l1 = *(const bf16x8*)(pl + (tile*2+1)*512 + (size_t)lane*8);
  return q;
}

// ---- GAP: mean over HW per (b,c) ----
__global__ __launch_bounds__(256) void k_gap(const float* __restrict__ f, float* __restrict__ gap){
  int bc = blockIdx.x;
  const float* row = f + (size_t)bc * HW_;
  float s = 0.f;
  for (int i = threadIdx.x; i < HW_; i += 256) s += row[i];
  #pragma unroll
  for (int off = 32; off; off >>= 1) s += __shfl_down(s, off);
  __shared__ float red[4];
  int lane = threadIdx.x & 63, wv = threadIdx.x >> 6;
  if (lane == 0) red[wv] = s;
  __syncthreads();
  if (threadIdx.x == 0) gap[bc] = (red[0]+red[1]+red[2]+red[3]) * (1.0f/HW_);
}

// ---- conv1d(k=3)+sigmoid, rank-1 scores, softmax over i -> bf16 hi/lo in B-frag layout ----
__global__ __launch_bounds__(256) void k_attc2(const float* __restrict__ gap,
    const float* __restrict__ wq1, const float* __restrict__ bq1,
    const float* __restrict__ wk1, const float* __restrict__ bk1,
    u16* __restrict__ ath, u16* __restrict__ atl){
  int b = blockIdx.x >> 8;
  int j = blockIdx.x & 255;
  int i = threadIdx.x;
  const float* g = gap + b*C_;
  float gm1 = (i > 0)      ? g[i-1] : 0.f;
  float g0  = g[i];
  float gp1 = (i < C_-1)   ? g[i+1] : 0.f;
  float keyv = wk1[0]*gm1 + wk1[1]*g0 + wk1[2]*gp1 + bk1[0];
  keyv = 1.f/(1.f+__expf(-keyv));
  float qm1 = (j > 0)      ? g[j-1] : 0.f;
  float q0  = g[j];
  float qp1 = (j < C_-1)   ? g[j+1] : 0.f;
  float qv = wq1[0]*qm1 + wq1[1]*q0 + wq1[2]*qp1 + bq1[0];
  qv = 1.f/(1.f+__expf(-qv));
  float s = keyv * qv;
  __shared__ float red[256];
  red[i] = s; __syncthreads();
  for (int st = 128; st > 0; st >>= 1){ if (i < st) red[i] = fmaxf(red[i], red[i+st]); __syncthreads(); }
  float mx = red[0]; __syncthreads();
  float e = __expf(s - mx);
  red[i] = e; __syncthreads();
  for (int st = 128; st > 0; st >>= 1){ if (i < st) red[i] += red[i+st]; __syncthreads(); }
  float sum = red[0];
  float x = e / sum;
  u16 hb = f2bf(x);
  size_t o = (((size_t)b*16 + (j>>4))*8 + (i>>5))*512 + (((i&31)>>3)*16 + (j&15))*8 + (i&7);
  ath[o] = hb;
  atl[o] = f2bf(x - bf2f(hb));
}

// ---- convert wq2/wk2/wv2 -> bf16 hi/lo A-frag layout; K pre-scaled by log2e ----
__global__ __launch_bounds__(256) void k_wcvt(const float* __restrict__ wq,
    const float* __restrict__ wk, const float* __restrict__ wv,
    u16* __restrict__ wbh, u16* __restrict__ wbl){
  int n = blockIdx.x*256 + threadIdx.x;     // 0..49151
  int mz = n >> 14; int idx = n & 16383;
  int e = idx >> 8, c = idx & 255;
  const float* w = (mz==0) ? wq : ((mz==1) ? wk : wv);
  float x = w[idx] * ((mz==1) ? LOG2E_ : 1.0f);
  u16 hb = f2bf(x);
  size_t widx = (((size_t)mz*4 + (e>>4))*8 + (c>>5))*512 + (((c&31)>>3)*16 + (e&15))*8 + (c&7);
  wbh[widx] = hb;
  wbl[widx] = f2bf(x - bf2f(hb));
}

// ---- q/k/v projections via MFMA. grid (B, 144, 6): mz = z>>1, mh = z&1 ----
__global__ __launch_bounds__(64) void k_proj6(const float* __restrict__ f,
    const u16* __restrict__ wbh, const u16* __restrict__ wbl,
    const float* __restrict__ bq, const float* __restrict__ bk, const float* __restrict__ bv,
    u16* __restrict__ qh, u16* __restrict__ qlo,
    u16* __restrict__ kh, u16* __restrict__ klo,
    u16* __restrict__ vh, u16* __restrict__ vlo){
  int b = blockIdx.x; int p0 = blockIdx.y*16;
  int mz = blockIdx.z >> 1, mh = blockIdx.z & 1;
  int lane = threadIdx.x; int l15 = lane & 15, g = lane >> 4;
  const float* fb = f + (size_t)b*SB_ + p0 + l15;
  const u16* wh = wbh + (size_t)mz*16384;
  const u16* wl = wbl + (size_t)mz*16384;
  const float* bi = (mz==0) ? bq : ((mz==1) ? bk : bv);
  const float bsc = (mz==1) ? LOG2E_ : 1.0f;
  f32x4 c1[2], c2[2], c3[2];
  #pragma unroll
  for (int m = 0; m < 2; m++){
    c1[m] = (f32x4){0.f,0.f,0.f,0.f};
    c2[m] = (f32x4){0.f,0.f,0.f,0.f};
    c3[m] = (f32x4){0.f,0.f,0.f,0.f};
  }
  #pragma unroll
  for (int ks = 0; ks < 8; ks++){
    int cb = ks*32 + g*8;
    float fe[8];
    #pragma unroll
    for (int u = 0; u < 8; u++) fe[u] = fb[(size_t)(cb + u)*HW_];
    union { unsigned w[4]; bf16x8 v; } FH, FL;
    #pragma unroll
    for (int u = 0; u < 4; u++) split2(fe[2*u], fe[2*u+1], FH.w[u], FL.w[u]);
    #pragma unroll
    for (int ml = 0; ml < 2; ml++){
      int m = mh*2 + ml;
      bf16x8 awh = *(const bf16x8*)(wh + ((size_t)m*8 + ks)*512 + (size_t)lane*8);
      bf16x8 awl = *(const bf16x8*)(wl + ((size_t)m*8 + ks)*512 + (size_t)lane*8);
      c1[ml] = MFMA16(awh, FH.v, c1[ml]);
      c2[ml] = MFMA16(awh, FL.v, c2[ml]);
      c3[ml] = MFMA16(awl, FH.v, c3[ml]);
    }
  }
  if (mz < 2){
    u16* ohb = (mz==0 ? qh : kh);
    u16* olb = (mz==0 ? qlo: klo);
    size_t tb = ((size_t)b*144 + blockIdx.y)*2;
    #pragma unroll
    for (int ml = 0; ml < 2; ml++){
      int m = mh*2 + ml;
      float x0 = c1[ml][0]+c2[ml][0]+c3[ml][0] + bi[m*16+g*4+0]*bsc;
      float x1 = c1[ml][1]+c2[ml][1]+c3[ml][1] + bi[m*16+g*4+1]*bsc;
      float x2 = c1[ml][2]+c2[ml][2]+c3[ml][2] + bi[m*16+g*4+2]*bsc;
      float x3 = c1[ml][3]+c2[ml][3]+c3[ml][3] + bi[m*16+g*4+3]*bsc;
      union { unsigned w[2]; uint2 v2; } H, L;
      split2(x0, x1, H.w[0], L.w[0]);
      split2(x2, x3, H.w[1], L.w[1]);
      int kc = mh;
      int gc = ml*2 + (g >> 1);
      int ub = (g & 1)*4;
      size_t idx = (tb + kc)*512 + (gc*16 + l15)*8 + ub;
      *(uint2*)(ohb + idx) = H.v2;
      *(uint2*)(olb + idx) = L.v2;
    }
  } else {
    int ic = blockIdx.y >> 1;
    int half = blockIdx.y & 1;
    int gg = half*2 + (l15 >> 3);
    int uu = l15 & 7;
    size_t vb0 = ((size_t)b*72 + ic)*4;
    #pragma unroll
    for (int ml = 0; ml < 2; ml++){
      int m = mh*2 + ml;
      #pragma unroll
      for (int r = 0; r < 4; r++){
        int e = m*16 + g*4 + r;
        float x = c1[ml][r] + c2[ml][r] + c3[ml][r] + bi[e];
        u16 hb = f2bf(x);
        size_t idx = (vb0 + m)*512 + (gg*16 + (g*4 + r))*8 + uu;
        vh[idx] = hb;
        vlo[idx] = f2bf(x - bf2f(hb));
      }
    }
  }
}

// ---- pass 1: partial row sums l_i = sum_j exp2(s'). grid (B, 72, 9) ----
__global__ __launch_bounds__(64,2) void k_stats6(
    const u16* __restrict__ qh, const u16* __restrict__ qlo,
    const u16* __restrict__ kh, const u16* __restrict__ klo,
    float* __restrict__ lpart){
  int b = blockIdx.x; int it0 = blockIdx.y; int jz = blockIdx.z;
  int lane = threadIdx.x; int l15 = lane & 15, g = lane >> 4;
  const size_t b144 = (size_t)b*144;
  KFrag kf0 = ldfrag(kh, klo, b144 + it0*2,     lane);
  KFrag kf1 = ldfrag(kh, klo, b144 + it0*2 + 1, lane);
  float lsum[8];
  #pragma unroll
  for (int x = 0; x < 8; x++) lsum[x] = 0.f;
  size_t qb0 = b144 + jz*16;
  #pragma unroll
  for (int t = 0; t < 16; t++){
    KFrag q = ldfrag(qh, qlo, qb0 + t, lane);
    #pragma unroll
    for (int isub = 0; isub < 2; isub++){
      const KFrag& kf = isub ? kf1 : kf0;
      f32x4 c1 = {0.f,0.f,0.f,0.f}, c2 = {0.f,0.f,0.f,0.f}, c3 = {0.f,0.f,0.f,0.f};
      c1 = MFMA16(kf.h0, q.h0, c1);
      c2 = MFMA16(kf.h0, q.l0, c2);
      c3 = MFMA16(kf.l0, q.h0, c3);
      c1 = MFMA16(kf.h1, q.h1, c1);
      c2 = MFMA16(kf.h1, q.l1, c2);
      c3 = MFMA16(kf.l1, q.h1, c3);
      #pragma unroll
      for (int r = 0; r < 4; r++) lsum[isub*4+r] += __builtin_exp2f(c1[r] + c2[r] + c3[r]);
    }
  }
  #pragma unroll
  for (int mk = 1; mk < 16; mk <<= 1){
    #pragma unroll
    for (int x = 0; x < 8; x++) lsum[x] += __shfl_xor(lsum[x], mk);
  }
  if (l15 == 0){
    float* lp = lpart + ((size_t)jz*B_ + b)*HW_ + it0*32;
    #pragma unroll
    for (int isub = 0; isub < 2; isub++)
      #pragma unroll
      for (int r = 0; r < 4; r++) lp[isub*16 + g*4 + r] = lsum[isub*4+r];
  }
}

// ---- lrl = -log2(sum of 9 partials) ----
__global__ __launch_bounds__(256) void k_lrl9(const float* __restrict__ lpart, float* __restrict__ lrl){
  int i = blockIdx.x*256 + threadIdx.x;
  const int BH = B_*HW_;
  float s = 0.f;
  #pragma unroll
  for (int p = 0; p < 9; p++) s += lpart[(size_t)p*BH + i];
  lrl[i] = -__builtin_log2f(s);
}

// ---- pass 2: partial GS via 32x32 MFMA; P-relayout via permlane32_swap (no LDS in loop). ----
// grid (B, 72, 9): j-tile 32, i range 256 (8 chunks of 32).
__global__ __launch_bounds__(64) void k_gs8(
    const u16* __restrict__ qh, const u16* __restrict__ qlo,
    const u16* __restrict__ kh, const u16* __restrict__ klo,
    const u16* __restrict__ vh, const u16* __restrict__ vlo,
    const float* __restrict__ lrl, float* __restrict__ gsp){
  int b = blockIdx.x; int jt32 = blockIdx.y; int iz = blockIdx.z;
  int j0 = jt32*32;
  int lane = threadIdx.x;
  int l31 = lane & 31, h = lane >> 5, l15q = lane & 15, lh = l31 >> 4;
  __shared__ __align__(16) float GT[2048];   // 8KB epilogue transpose only
  const size_t b144 = (size_t)b*144;
  // persistent Q B-frags (32x32): col j = j0+l31, k(e) = m*16 + h*8 + u
  bf16x8 qfh[4], qfl[4];
  size_t qtile = (b144 + jt32*2 + lh)*2;
  #pragma unroll
  for (int m = 0; m < 4; m++){
    size_t qa = (qtile + (m>>1))*512 + (size_t)((((m&1)*2 + h)*16 + l15q)*8);
    qfh[m] = *(const bf16x8*)(qh + qa);
    qfl[m] = *(const bf16x8*)(qlo + qa);
  }
  f32x16 acc0 = {}, acc1 = {};
  const float* lrlb = lrl + b*HW_;
  #pragma unroll 2
  for (int ic = 0; ic < 8; ic++){
    int i0c = iz*256 + ic*32;
    // K A-frags: row i = i0c+l31, k(e) = m*16 + h*8 + u
    bf16x8 kfh[4], kfl[4];
    size_t ktile = (b144 + iz*16 + ic*2 + lh)*2;
    #pragma unroll
    for (int m = 0; m < 4; m++){
      size_t ka = (ktile + (m>>1))*512 + (size_t)((((m&1)*2 + h)*16 + l15q)*8);
      kfh[m] = *(const bf16x8*)(kh + ka);
      kfl[m] = *(const bf16x8*)(klo + ka);
    }
    // V A-frags: row e = eh*32+l31, k(i) = n*16 + h*8 + u
    bf16x8 vfh[2][2], vfl[2][2];
    size_t vslot = ((size_t)b*72 + iz*8 + ic)*4;
    #pragma unroll
    for (int eh = 0; eh < 2; eh++)
      #pragma unroll
      for (int n = 0; n < 2; n++){
        size_t va = (vslot + eh*2 + lh)*512 + (size_t)(((2*n + h)*16 + l15q)*8);
        vfh[eh][n] = *(const bf16x8*)(vh + va);
        vfl[eh][n] = *(const bf16x8*)(vlo + va);
      }
    // lrl for rows i = i0c + (r&3) + 8*(r>>2) + 4h
    f32x4 lr[4];
    #pragma unroll
    for (int rr = 0; rr < 4; rr++) lr[rr] = *(const f32x4*)&lrlb[i0c + rr*8 + 4*h];
    // S: D[i][j], col=l31=j, row=(r&3)+8*(r>>2)+4h
    f32x16 c1 = {}, c23 = {};
    #pragma unroll
    for (int m = 0; m < 4; m++){
      c1  = MFMA32(kfh[m], qfh[m], c1);
      c23 = MFMA32(kfh[m], qfl[m], c23);
      c23 = MFMA32(kfl[m], qfh[m], c23);
    }
    // P = exp2(s' + lrl_i), packed: W[w] = (p[2w], p[2w+1]) = i pairs (8*(w>>1)+4h+2*(w&1), +1)
    unsigned Wh[8], Wl[8];
    #pragma unroll
    for (int w = 0; w < 8; w++){
      float p0 = __builtin_exp2f(c1[2*w]   + c23[2*w]   + lr[(2*w)>>2][(2*w)&3]);
      float p1 = __builtin_exp2f(c1[2*w+1] + c23[2*w+1] + lr[(2*w+1)>>2][(2*w+1)&3]);
      split2(p0, p1, Wh[w], Wl[w]);
    }
    // relayout to PV B-frags: swap(Ww, Ww+2) -> words for k = n*16 + h*8 + u
    PSWAP(Wh[0], Wh[2]); PSWAP(Wh[1], Wh[3]);
    PSWAP(Wh[4], Wh[6]); PSWAP(Wh[5], Wh[7]);
    PSWAP(Wl[0], Wl[2]); PSWAP(Wl[1], Wl[3]);
    PSWAP(Wl[4], Wl[6]); PSWAP(Wl[5], Wl[7]);
    union { unsigned w[4]; bf16x8 v; } ph0, ph1, pl0, pl1;
    ph0.w[0]=Wh[0]; ph0.w[1]=Wh[1]; ph0.w[2]=Wh[2]; ph0.w[3]=Wh[3];
    ph1.w[0]=Wh[4]; ph1.w[1]=Wh[5]; ph1.w[2]=Wh[6]; ph1.w[3]=Wh[7];
    pl0.w[0]=Wl[0]; pl0.w[1]=Wl[1]; pl0.w[2]=Wl[2]; pl0.w[3]=Wl[3];
    pl1.w[0]=Wl[4]; pl1.w[1]=Wl[5]; pl1.w[2]=Wl[6]; pl1.w[3]=Wl[7];
    // PV: D[e][j] += V*P
    acc0 = MFMA32(vfh[0][0], ph0.v, acc0);
    acc0 = MFMA32(vfh[0][0], pl0.v, acc0);
    acc0 = MFMA32(vfl[0][0], ph0.v, acc0);
    acc0 = MFMA32(vfh[0][1], ph1.v, acc0);
    acc0 = MFMA32(vfh[0][1], pl1.v, acc0);
    acc0 = MFMA32(vfl[0][1], ph1.v, acc0);
    acc1 = MFMA32(vfh[1][0], ph0.v, acc1);
    acc1 = MFMA32(vfh[1][0], pl0.v, acc1);
    acc1 = MFMA32(vfl[1][0], ph0.v, acc1);
    acc1 = MFMA32(vfh[1][1], ph1.v, acc1);
    acc1 = MFMA32(vfh[1][1], pl1.v, acc1);
    acc1 = MFMA32(vfl[1][1], ph1.v, acc1);
  }
  // epilogue: transpose through LDS -> full-line stores
  #pragma unroll
  for (int r = 0; r < 16; r++){
    int erow = (r&3) + 8*(r>>2) + 4*h;
    GT[erow*32 + l31]        = acc0[r];
    GT[(32 + erow)*32 + l31] = acc1[r];
  }
  LDS_FENCE();
  float* gb = gsp + ((size_t)iz*B_ + b)*E_*HW_;
  #pragma unroll
  for (int itx = 0; itx < 8; itx++){
    int n = (itx*64 + lane)*4;
    f32x4 vv = *(const f32x4*)&GT[n];
    int e = n >> 5, jj = n & 31;
    *(f32x4*)&gb[(size_t)e*HW_ + j0 + jj] = vv;
  }
}

// ---- gs = sum of 9 gsp partials ----
__global__ __launch_bounds__(256) void k_gsum9(const float* __restrict__ gsp, float* __restrict__ gs){
  const size_t N = (size_t)B_*E_*HW_;
  size_t n = ((size_t)blockIdx.x*256 + threadIdx.x)*4;
  f32x4 s = *(const f32x4*)(gsp + n);
  #pragma unroll
  for (int p = 1; p < 9; p++) s += *(const f32x4*)(gsp + (size_t)p*N + n);
  *(f32x4*)(gs + n) = s;
}

// ---- gsout[c,s] = sum_e watt[c,e]*gs[e,s] + batt[c] ----
__global__ __launch_bounds__(256) void k_gsout2(const float* __restrict__ gs,
    const float* __restrict__ watt, const float* __restrict__ batt,
    float* __restrict__ gsout){
  int b = blockIdx.x; int sc = blockIdx.y; int cc0 = blockIdx.z * 16;
  int s = sc*256 + threadIdx.x;
  const float* gb = gs + (size_t)b*E_*HW_ + s;
  float acc[16];
  #pragma unroll
  for (int x = 0; x < 16; x++) acc[x] = 0.f;
  for (int e = 0; e < E_; e++){
    float gv = gb[(size_t)e*HW_];
    #pragma unroll
    for (int x = 0; x < 16; x++) acc[x] += watt[(cc0+x)*E_ + e] * gv;   // uniform -> s_load
  }
  float* ob = gsout + (size_t)b*SB_ + (size_t)cc0*HW_ + s;
  #pragma unroll
  for (int x = 0; x < 16; x++) ob[(size_t)x*HW_] = acc[x] + batt[cc0 + x];
}

// ---- final: gc via MFMA, fused out = f*gc*(gsout+1). grid (B, 144, 4) ----
__global__ __launch_bounds__(64) void k_final5(const float* __restrict__ f,
    const u16* __restrict__ ath, const u16* __restrict__ atl,
    float* __restrict__ inout){
  int b = blockIdx.x; int s0 = blockIdx.y*16; int z = blockIdx.z;
  int lane = threadIdx.x; int l15 = lane & 15, g = lane >> 4;
  const float* fb = f + (size_t)b*SB_;
  bf16x8 Ah[8], Al[8];
  const float* arow = fb + (size_t)(s0 + l15)*C_;
  #pragma unroll
  for (int ks = 0; ks < 8; ks++){
    int cbase = ks*32 + g*8;
    float4 f4a = *(const float4*)&arow[cbase];
    float4 f4b = *(const float4*)&arow[cbase + 4];
    union { unsigned w[4]; bf16x8 v; } H, L;
    split2(f4a.x, f4a.y, H.w[0], L.w[0]);
    split2(f4a.z, f4a.w, H.w[1], L.w[1]);
    split2(f4b.x, f4b.y, H.w[2], L.w[2]);
    split2(f4b.z, f4b.w, H.w[3], L.w[3]);
    Ah[ks] = H.v; Al[ks] = L.v;
  }
  const u16* abz_h = ath + (size_t)b*65536;
  const u16* abz_l = atl + (size_t)b*65536;
  f32x4 acc[4];
  #pragma unroll
  for (int q = 0; q < 4; q++) acc[q] = (f32x4){0.f,0.f,0.f,0.f};
  #pragma unroll
  for (int q = 0; q < 4; q++){
    int jt = z*4 + q;
    #pragma unroll
    for (int ks = 0; ks < 8; ks++){
      bf16x8 Bh = *(const bf16x8*)(abz_h + ((size_t)jt*8 + ks)*512 + (size_t)lane*8);
      bf16x8 Bl = *(const bf16x8*)(abz_l + ((size_t)jt*8 + ks)*512 + (size_t)lane*8);
      acc[q] = MFMA16(Ah[ks], Bh, acc[q]);
      acc[q] = MFMA16(Ah[ks], Bl, acc[q]);
      acc[q] = MFMA16(Al[ks], Bh, acc[q]);
    }
  }
  float* ob = inout + (size_t)b*SB_;
  #pragma unroll
  for (int q = 0; q < 4; q++){
    #pragma unroll
    for (int r = 0; r < 4; r++){
      int p = s0 + g*4 + r;
      int j = (z*4+q)*16 + l15;
      size_t n = (size_t)p*C_ + j;
      float fx = fb[n];
      float gso = ob[n];
      ob[n] = acc[q][r] * fx * (gso + 1.f);
    }
  }
}

extern "C" void kernel_launch(void* const* d_in, const int* in_sizes, int n_in,
                              void* d_out, int out_size, void* d_ws, size_t ws_size,
                              hipStream_t stream){
  const float* f    = (const float*)d_in[0];
  const float* wq1  = (const float*)d_in[1];
  const float* bq1  = (const float*)d_in[2];
  const float* wk1  = (const float*)d_in[3];
  const float* bk1  = (const float*)d_in[4];
  const float* wq2  = (const float*)d_in[5];
  const float* bq2  = (const float*)d_in[6];
  const float* wk2  = (const float*)d_in[7];
  const float* bk2  = (const float*)d_in[8];
  const float* wv2  = (const float*)d_in[9];
  const float* bv2  = (const float*)d_in[10];
  const float* watt = (const float*)d_in[11];
  const float* batt = (const float*)d_in[12];
  float* out = (float*)d_out;
  char* W = (char*)d_ws;

  // byte offsets (16B aligned); total = 64,380,928 B (~61.4 MiB)
  float* gap   = (float*)(W + 0);          //     8192
  u16*   ath   = (u16*)  (W + 8192);       //  1048576
  u16*   atl   = (u16*)  (W + 1056768);    //  1048576
  float* lpart = (float*)(W + 2105344);    //   663552 (9 x B x HW)
  float* lrl   = (float*)(W + 2768896);    //    73728
  float* gsp   = (float*)(W + 2842624);    // 42467328 (9 x B x E x HW)
  float* gs    = (float*)(W + 45309952);   //  4718592
  u16* qh  = (u16*)(W + 50028544);         //  2359296 each below
  u16* qlo = (u16*)(W + 52387840);
  u16* kh  = (u16*)(W + 54747136);
  u16* klo = (u16*)(W + 57106432);
  u16* vh  = (u16*)(W + 59465728);
  u16* vlo = (u16*)(W + 61825024);
  u16* wbh = (u16*)(W + 64184320);         //    98304
  u16* wbl = (u16*)(W + 64282624);         //    98304

  k_gap   <<<B_*C_,             256, 0, stream>>>(f, gap);
  k_attc2 <<<B_*C_,             256, 0, stream>>>(gap, wq1, bq1, wk1, bk1, ath, atl);
  k_wcvt  <<<192,               256, 0, stream>>>(wq2, wk2, wv2, wbh, wbl);
  k_proj6 <<<dim3(B_, 144, 6),   64, 0, stream>>>(f, wbh, wbl, bq2, bk2, bv2,
                                                  qh, qlo, kh, klo, vh, vlo);
  k_stats6<<<dim3(B_, 72, 9),    64, 0, stream>>>(qh, qlo, kh, klo, lpart);
  k_lrl9  <<<B_*HW_/256,        256, 0, stream>>>(lpart, lrl);
  k_gs8   <<<dim3(B_, 72, 9),    64, 0, stream>>>(qh, qlo, kh, klo, vh, vlo, lrl, gsp);
  k_gsum9 <<<B_*E_*HW_/1024,    256, 0, stream>>>(gsp, gs);
  k_gsout2<<<dim3(B_, 9, 16),   256, 0, stream>>>(gs, watt, batt, out);
  k_final5<<<dim3(B_, 144, 4),   64, 0, stream>>>(f, ath, atl, out);
}